// Round 5
// baseline (535.413 us; speedup 1.0000x reference)
//
#include <hip/hip_runtime.h>
#include <stdint.h>

#define EPSF 1e-5f

typedef _Float16 h8_t __attribute__((ext_vector_type(8)));
typedef float f4_t __attribute__((ext_vector_type(4)));

#define BB 64
#define CC 256
#define HH 32
#define WW 32
#define HP 34
#define WP 34
#define PADIMG (HP*WP*CC)      // halfwords per image
#define PADTOT (BB*PADIMG)

// ---- stats layout (float offsets); every slot written every launch
#define S_GSUM   0     // 64: per-group sum |w1|
#define S_GMAX   64    // 64: per-group max |w1|
#define S_W1S    128   // 64
#define S_W1Q    192   // 64
#define S_W2S    256   // 64
#define S_W2Q    320   // 64
#define S_PA2    384   // 3 (written by fused block 0, read by conv1)
#define S_INDCH  400   // 256
#define S_BN2SC  656   // 256
#define S_BN2SH  912   // 256

// ---- ws byte offsets
#define OFF_STATS 0
#define OFF_A1    8192
#define OFF_A2    (OFF_A1 + PADTOT*2)
#define OFF_W1T   (OFF_A2 + PADTOT*2)
#define OFF_W2T   (OFF_W1T + 9*CC*CC*2)

__device__ __forceinline__ void async_load16(void* lds, const void* g) {
  __builtin_amdgcn_global_load_lds(
      reinterpret_cast<uint32_t __attribute__((address_space(1)))*>((uintptr_t)g),
      reinterpret_cast<uint32_t __attribute__((address_space(3)))*>((uint32_t)(uintptr_t)lds),
      16, 0, 0);
}

#define WAITV(N) asm volatile("s_waitcnt vmcnt(" #N ")" ::: "memory")

__device__ __forceinline__ float wave_sum(float v) {
  for (int o = 32; o; o >>= 1) v += __shfl_down(v, o);
  return v;
}
__device__ __forceinline__ float wave_max(float v) {
  for (int o = 32; o; o >>= 1) v = fmaxf(v, __shfl_down(v, o));
  return v;
}

__device__ __forceinline__ void softmax3(const float* l, float* out) {
  float m = fmaxf(fmaxf(l[0], l[1]), l[2]);
  float e0 = expf(l[0] - m), e1 = expf(l[1] - m), e2 = expf(l[2] - m);
  float inv = 1.f / (e0 + e1 + e2);
  out[0] = e0 * inv; out[1] = e1 * inv; out[2] = e2 * inv;
}

// quant-mix helper (activations): clip[0,1] then 2/4/8-bit STE mix
__device__ __forceinline__ float qmix_act(float v, float p0, float p1, float p2) {
  float cl = fminf(fmaxf(v, 0.f), 1.f);
  return p0 * (rintf(cl * 3.f) / 3.f) + p1 * (rintf(cl * 15.f) / 15.f)
       + p2 * (rintf(cl * 255.f) / 255.f);
}

// ---------------- per-group stats: one pass over w1 and w2 ----------------
__global__ void k_stats(const float* __restrict__ w1, const float* __restrict__ w2,
                        float* stats) {
  __shared__ float red[4][4];
  int bid = blockIdx.x, t = threadIdx.x;
  int lane = t & 63, w = t >> 6;
  if (bid < 64) {
    const float* p = w1 + bid * 9216;
    float sa = 0.f, s = 0.f, q = 0.f, mx = 0.f;
    for (int i = t; i < 9216; i += 256) {
      float v = p[i];
      float a = fabsf(v);
      sa += a; s += v; q += v * v; mx = fmaxf(mx, a);
    }
    sa = wave_sum(sa); s = wave_sum(s); q = wave_sum(q); mx = wave_max(mx);
    if (lane == 0) { red[w][0] = sa; red[w][1] = s; red[w][2] = q; red[w][3] = mx; }
    __syncthreads();
    if (t == 0) {
      float a = 0, b = 0, c = 0, d = 0;
      for (int k = 0; k < 4; ++k) {
        a += red[k][0]; b += red[k][1]; c += red[k][2]; d = fmaxf(d, red[k][3]);
      }
      stats[S_GSUM + bid] = a;
      stats[S_W1S + bid] = b;
      stats[S_W1Q + bid] = c;
      stats[S_GMAX + bid] = d;
    }
  } else {
    int g = bid - 64;
    const float* p = w2 + (size_t)t * 2304 + g * 36;
    float s = 0.f, q = 0.f;
#pragma unroll
    for (int i = 0; i < 36; ++i) { float v = p[i]; s += v; q += v * v; }
    s = wave_sum(s); q = wave_sum(q);
    if (lane == 0) { red[w][0] = s; red[w][1] = q; }
    __syncthreads();
    if (t == 0) {
      float a = 0, b = 0;
      for (int k = 0; k < 4; ++k) { a += red[k][0]; b += red[k][1]; }
      stats[S_W2S + g] = a;
      stats[S_W2Q + g] = b;
    }
  }
}

// ---------------- fused prep + wprep + aprep (+ borders) ----------------
// block 0          : conv1 epilogue consts (indicator, bn2, pa2)
// blocks 1..64     : weight quant+mix, 8 filters/block (32 blocks per tensor)
//                    -> fp16 [e][ci_oct][co][8], stores coalesce to 128B bursts
// blocks 65..2112  : bn1+relu+qmix act -> fp16 padded NHWC
// blocks 2113..2240: border zeroing
#define WPS 264
#define APR_STRIDE 264
__global__ void k_fused(const float* __restrict__ w1, const float* __restrict__ w2,
                        const float* __restrict__ xin, const float* __restrict__ thr_p,
                        const float* __restrict__ bn1g, const float* __restrict__ bn1b,
                        const float* __restrict__ bn1m, const float* __restrict__ bn1v,
                        const float* __restrict__ bn2g, const float* __restrict__ bn2b,
                        const float* __restrict__ bn2m, const float* __restrict__ bn2v,
                        const float* __restrict__ wl1, const float* __restrict__ al1,
                        const float* __restrict__ wl2, const float* __restrict__ al2,
                        float* __restrict__ stats,
                        _Float16* __restrict__ wt1, _Float16* __restrict__ wt2,
                        _Float16* __restrict__ a1, _Float16* __restrict__ a2) {
  int bid = blockIdx.x, t = threadIdx.x;

  if (bid == 0) {
    __shared__ float sind[64];
    if (t < 64) {
      float thr = thr_p[0];
      float mx = wave_max(stats[S_GMAX + t]);
      mx = __shfl(mx, 0);
      float norm = stats[S_GSUM + t] / mx / 9216.0f;
      float soft = 1.f / (1.f + expf(-(norm - thr)));
      float hard = (norm > thr) ? 1.f : 0.f;
      sind[t] = (hard - soft) + soft;
    }
    __syncthreads();
    stats[S_INDCH + t] = sind[t >> 2];
    float sc2 = bn2g[t] * (1.f / sqrtf(bn2v[t] + EPSF));
    stats[S_BN2SC + t] = sc2;
    stats[S_BN2SH + t] = bn2b[t] - bn2m[t] * sc2;
    if (t == 0) softmax3(al2, stats + S_PA2);
    return;
  }

  if (bid <= 64) {
    // ---- weight prep: 8 filters per block, 32 blocks per tensor
    __shared__ __attribute__((aligned(16))) _Float16 lds[8 * 9 * WPS];
    __shared__ float sM, sSD, sP[3];
    int which = (bid - 1) >> 5;            // 0: blocks 1..32 (w1), 1: 33..64 (w2)
    int o0 = ((bid - 1) & 31) * 8;         // first of 8 filters (0..248)
    if (t < 64) {
      float thr = thr_p[0];
      float mx = wave_max(stats[S_GMAX + t]);
      mx = __shfl(mx, 0);
      float norm = stats[S_GSUM + t] / mx / 9216.0f;
      float soft = 1.f / (1.f + expf(-(norm - thr)));
      float hard = (norm > thr) ? 1.f : 0.f;
      float iv = (hard - soft) + soft;
      float gate = (iv > 0.f) ? 1.f : 0.f;
      float ng = wave_sum(gate);
      float s = wave_sum(gate * stats[(which ? S_W2S : S_W1S) + t]);
      float q = wave_sum(gate * stats[(which ? S_W2Q : S_W1Q) + t]);
      if (t == 0) {
        float cnt = ng * 9216.0f;
        float m = s / cnt;
        float v = (q - cnt * m * m) / (cnt - 1.0f);
        sM = m; sSD = sqrtf(fmaxf(v, 0.f));
        softmax3(which ? wl2 : wl1, sP);
      }
    }
    __syncthreads();
    const float* w = (which ? w2 : w1) + (size_t)o0 * 2304;
    float mean = sM, sd = sSD + EPSF;
    float p0 = sP[0], p1 = sP[1], p2 = sP[2];
#pragma unroll
    for (int it = 0; it < 72; ++it) {
      int f = it * 256 + t;          // 0..18431 over 8 filters x 2304
      float v = w[f];
      float wn = fminf(fmaxf((v - mean) / sd, -1.f), 1.f);
      float u0 = rintf((wn + 1.f) * 0.5f * 3.f) / 3.f;
      float u1 = rintf((wn + 1.f) * 0.5f * 15.f) / 15.f;
      float u2 = rintf((wn + 1.f) * 0.5f * 255.f) / 255.f;
      float mix = p0 * (2.f * u0 - 1.f) + p1 * (2.f * u1 - 1.f) + p2 * (2.f * u2 - 1.f);
      int ff = f / 2304;
      int rem = f - 2304 * ff;       // ci*9 + e
      int ci = rem / 9;
      int e = rem - 9 * ci;
      lds[(ff * 9 + e) * WPS + ci] = (_Float16)mix;
    }
    __syncthreads();
    // store layout: [e][cq(32)][co(256)][8]; 8 filters -> 128B bursts
    _Float16* dstW = (which ? wt2 : wt1);
#pragma unroll
    for (int it = 0; it < 9; ++it) {
      int qid = it * 256 + t;        // 0..2303
      int ff = qid & 7, pair = qid >> 3;
      int e = pair >> 5, cq = pair & 31;
      *(h8_t*)(dstW + ((size_t)(e * 32 + cq) * 256 + o0 + ff) * 8) =
          *(const h8_t*)(lds + (ff * 9 + e) * WPS + cq * 8);
    }
    return;
  }

  int ab = bid - 65;
  if (ab >= BB * HH) {
    // ---- border zeroing
    int b = ab - BB * HH;            // 0..127
    _Float16* img = (b >= BB ? a2 : a1) + (size_t)(b & 63) * PADIMG;
    uint64_t* u = (uint64_t*)img;
#pragma unroll
    for (int it = 0; it < 17; ++it) {
      int idx = it * 256 + t;          // 0..4351: rows 0 & 33 (full)
      int r33 = (idx >= 2176);
      u[(size_t)(r33 ? 33 * WP * 64 : 0) + (idx - (r33 ? 2176 : 0))] = 0ull;
    }
#pragma unroll
    for (int it = 0; it < 16; ++it) {
      int idx = it * 256 + t;          // 0..4095: cols 0/33 rows 1..32
      int p = idx >> 6;
      int y = 1 + (p >> 1), x = (p & 1) ? 33 : 0;
      u[(size_t)(y * WP + x) * 64 + (idx & 63)] = 0ull;
    }
    return;
  }

  // ---- act prep
  __shared__ __attribute__((aligned(16))) _Float16 lds[32 * APR_STRIDE];
  __shared__ float sBsc[256], sBsh[256], sPa[3];
  {
    float sc1 = bn1g[t] * (1.f / sqrtf(bn1v[t] + EPSF));
    sBsc[t] = sc1;
    sBsh[t] = bn1b[t] - bn1m[t] * sc1;
    if (t == 0) softmax3(al1, sPa);
  }
  __syncthreads();
  int n = ab >> 5, y = ab & 31;
  int x4 = (t & 7) * 4, c0 = t >> 3;
  float pa0 = sPa[0], pa1 = sPa[1], pa2 = sPa[2];
#pragma unroll
  for (int it = 0; it < 8; ++it) {
    int c = it * 32 + c0;
    const float* src = xin + ((size_t)(n * CC + c) * HH + y) * WW + x4;
    float4 v = *(const float4*)src;
    float sc = sBsc[c], sh = sBsh[c];
#pragma unroll
    for (int k = 0; k < 4; ++k) {
      float q = qmix_act((&v.x)[k] * sc + sh, pa0, pa1, pa2);
      lds[(x4 + k) * APR_STRIDE + c] = (_Float16)q;
    }
  }
  __syncthreads();
  _Float16* orow = a1 + ((size_t)(n * HP + (y + 1)) * WP + 1) * CC;
#pragma unroll
  for (int it = 0; it < 4; ++it) {
    int qid = it * 256 + t;
    int xx = qid >> 5, c8 = (qid & 31) * 8;
    *(h8_t*)(orow + xx * CC + c8) = *(const h8_t*)(lds + xx * APR_STRIDE + c8);
  }
}

// ---------------- implicit-GEMM conv, 128x128 tile, fp16 MFMA ----------------
// Weights-direct schedule (R3) + forced 4 waves/SIMD:
//  - LDS holds ONLY the act tile (staged once per kc, 28 KB) -> 2 barriers/kc
//  - weight B-fragments straight from global (L2-resident [e][cq][co][8]) into
//    double-buffered registers; counted vmcnt, never drains mid-loop
//  - __launch_bounds__(256,4): cap VGPR at 128 -> 4 blocks/CU (R3 was 132 -> 3)
template <bool SW>
__global__ __launch_bounds__(256, 4) void k_conv(
    const _Float16* __restrict__ act,   // padded NHWC acts
    const _Float16* __restrict__ wts,   // [9][32][256][8] fp16
    const float* __restrict__ stats,
    _Float16* __restrict__ a2out,
    const float* __restrict__ resid,
    float* __restrict__ out) {
  __shared__ __attribute__((aligned(16))) _Float16 AT[224 * 64];   // act tile (rows 204..223 pad)
  const int tid = threadIdx.x;
  const int lane = tid & 63, wid = tid >> 6;
  const int xcd = blockIdx.x & 7;
  const int j = blockIdx.x >> 3;          // 0..127
  const int blk_co = j >> 6;
  const int blk_m = xcd * 64 + (j & 63);

  // ---- act tile geometry: 128 m-values = 4 rows of one image
  const int n0 = blk_m >> 3;
  const int y0 = (blk_m & 7) * 4;
  const _Float16* actbase = act + (size_t)(n0 * HP + y0) * WP * CC;

  const int wr = wid >> 1, wc = wid & 1;
  const int mrow = (SW ? wc : wr) * 64;   // act-operand row block
  const int wrow = (SW ? wr : wc) * 64;   // weight-operand co block (within 128)
  const int ksl = lane >> 4;              // k-octet (8-ch) within 32-ch step

  int trbase[4];
#pragma unroll
  for (int i = 0; i < 4; ++i) {
    int r = mrow + i * 16 + (lane & 15);
    trbase[i] = (r >> 5) * 34 + (r & 31);           // tile row for tap (0,0)
  }
  // per-lane halfword offset into weight layout [e][cq][co][8]
  const unsigned vbase = (unsigned)(ksl * 256 + blk_co * 128 + wrow + (lane & 15)) * 8u;

  f4_t acc[4][4];
  const f4_t z4 = {0.f, 0.f, 0.f, 0.f};
#pragma unroll
  for (int i = 0; i < 4; ++i)
#pragma unroll
    for (int j2 = 0; j2 < 4; ++j2) acc[i][j2] = z4;

  auto stageA = [&](int kcn) {
    const int kb = kcn * 64;
#pragma unroll
    for (int it = 0; it < 7; ++it) {
      int l = it * 256 + tid;                 // 1792 loads (uniform per wave)
      int tr = l >> 3, gg = l & 7;
      int yl = tr / 34, px = tr - yl * 34;
      async_load16(AT + l * 8,
                   actbase + ((size_t)yl * WP + px) * CC + kb + ((gg ^ (tr & 7)) * 8));
    }
  };

  h8_t fwA[4], fwB[4];
  auto loadW = [&](h8_t* dst, int e, int kcn, int kk) {
    const _Float16* p = wts + (size_t)((e * 32 + kcn * 8 + kk * 4) * 2048) + vbase;
#pragma unroll
    for (int i = 0; i < 4; ++i)
      dst[i] = *(const h8_t*)(p + i * 128);
  };

  auto step = [&](const h8_t* fw, int e, int kk) {
    const int de = (e / 3) * 34 + (e % 3);
    h8_t fa[4];
#pragma unroll
    for (int i = 0; i < 4; ++i) {
      int tr = trbase[i] + de;
      fa[i] = *(const h8_t*)(AT + ((tr * 64 + ((ksl ^ (tr & 7)) * 8)) ^ (kk * 32)));
    }
    __builtin_amdgcn_s_setprio(1);
#pragma unroll
    for (int i = 0; i < 4; ++i)
#pragma unroll
      for (int j2 = 0; j2 < 4; ++j2)
        acc[i][j2] = __builtin_amdgcn_mfma_f32_16x16x32_f16(
            SW ? fw[i] : fa[i], SW ? fa[j2] : fw[j2], acc[i][j2], 0, 0, 0);
    __builtin_amdgcn_s_setprio(0);
  };

  // prologue: queue = [stageA(7), fwA(4), fwB(4)]
  stageA(0);
  loadW(fwA, 0, 0, 0);
  loadW(fwB, 0, 0, 1);

#pragma unroll 1
  for (int kc = 0; kc < 4; ++kc) {
    // drain own stageA (+previous fwA); leaves newest 4 (fwB) in flight
    WAITV(4);
    __builtin_amdgcn_s_barrier();
    __builtin_amdgcn_sched_barrier(0);
#pragma unroll
    for (int t2 = 0; t2 < 9; ++t2) {
      if (t2 < 8) {
        step(fwA, t2, 0);
        loadW(fwA, t2 + 1, kc, 0);
        step(fwB, t2, 1);
        loadW(fwB, t2 + 1, kc, 1);
      } else {
        step(fwA, 8, 0);
        if (kc < 3) loadW(fwA, 0, kc + 1, 0);
        // prefetch stepB act fragments BEFORE the barrier (AT(kc) still valid)
        h8_t faB[4];
#pragma unroll
        for (int i = 0; i < 4; ++i) {
          int tr = trbase[i] + 70;           // tap (2,2)
          faB[i] = *(const h8_t*)(AT + ((tr * 64 + ((ksl ^ (tr & 7)) * 8)) ^ 32));
        }
        if (kc < 3) {
          asm volatile("s_waitcnt lgkmcnt(0)" ::: "memory");
          __builtin_amdgcn_sched_barrier(0);
          __builtin_amdgcn_s_barrier();
          __builtin_amdgcn_sched_barrier(0);
          stageA(kc + 1);
        }
        __builtin_amdgcn_s_setprio(1);
#pragma unroll
        for (int i = 0; i < 4; ++i)
#pragma unroll
          for (int j2 = 0; j2 < 4; ++j2)
            acc[i][j2] = __builtin_amdgcn_mfma_f32_16x16x32_f16(
                SW ? fwB[i] : faB[i], SW ? faB[j2] : fwB[j2], acc[i][j2], 0, 0, 0);
        __builtin_amdgcn_s_setprio(0);
        if (kc < 3) loadW(fwB, 0, kc + 1, 1);
      }
    }
  }

  const int quad = lane >> 4;
  const int cq = lane & 15;
  if (!SW) {
    const float pa0 = stats[S_PA2], pa1 = stats[S_PA2 + 1], pa2 = stats[S_PA2 + 2];
#pragma unroll
    for (int j2 = 0; j2 < 4; ++j2) {
      const int co = blk_co * 128 + wc * 64 + j2 * 16 + cq;
      const float sc = stats[S_BN2SC + co];
      const float sh = stats[S_BN2SH + co];
      const float ic = stats[S_INDCH + co];
#pragma unroll
      for (int i = 0; i < 4; ++i) {
        const int mbase = blk_m * 128 + wr * 64 + i * 16 + quad * 4;
#pragma unroll
        for (int rg = 0; rg < 4; ++rg) {
          const int m = mbase + rg;
          const int n = m >> 10, y = (m >> 5) & 31, x = m & 31;
          float h = fmaxf(acc[i][j2][rg] * sc + sh, 0.f) * ic;
          float q = qmix_act(h, pa0, pa1, pa2);
          a2out[((size_t)(n * HP + y + 1) * WP + (x + 1)) * CC + co] = (_Float16)q;
        }
      }
    }
  } else {
#pragma unroll
    for (int j2 = 0; j2 < 4; ++j2) {
      const int m = blk_m * 128 + wc * 64 + j2 * 16 + cq;
      const int n = m >> 10, y = (m >> 5) & 31, x = m & 31;
#pragma unroll
      for (int i = 0; i < 4; ++i) {
        const int cobase = blk_co * 128 + wr * 64 + i * 16 + quad * 4;
#pragma unroll
        for (int rg = 0; rg < 4; ++rg) {
          const int co = cobase + rg;
          const int idx = ((n * CC + co) << 10) + (y << 5) + x;
          out[idx] = acc[i][j2][rg] + resid[idx];
        }
      }
    }
  }
}

extern "C" void kernel_launch(void* const* d_in, const int* in_sizes, int n_in,
                              void* d_out, int out_size, void* d_ws, size_t ws_size,
                              hipStream_t stream) {
  const float* x    = (const float*)d_in[0];
  const float* w1   = (const float*)d_in[1];
  const float* w2   = (const float*)d_in[2];
  const float* bn1g = (const float*)d_in[3];
  const float* bn1b = (const float*)d_in[4];
  const float* bn1m = (const float*)d_in[5];
  const float* bn1v = (const float*)d_in[6];
  const float* bn2g = (const float*)d_in[7];
  const float* bn2b = (const float*)d_in[8];
  const float* bn2m = (const float*)d_in[9];
  const float* bn2v = (const float*)d_in[10];
  const float* thr  = (const float*)d_in[11];
  const float* wl1  = (const float*)d_in[12];
  const float* al1  = (const float*)d_in[13];
  const float* wl2  = (const float*)d_in[14];
  const float* al2  = (const float*)d_in[15];

  char* ws = (char*)d_ws;
  float* stats = (float*)(ws + OFF_STATS);
  _Float16* a1 = (_Float16*)(ws + OFF_A1);
  _Float16* a2 = (_Float16*)(ws + OFF_A2);
  _Float16* wt1 = (_Float16*)(ws + OFF_W1T);
  _Float16* wt2 = (_Float16*)(ws + OFF_W2T);
  float* out = (float*)d_out;

  k_stats<<<128, 256, 0, stream>>>(w1, w2, stats);
  k_fused<<<1 + 64 + BB * HH + 128, 256, 0, stream>>>(
      w1, w2, x, thr, bn1g, bn1b, bn1m, bn1v, bn2g, bn2b, bn2m, bn2v,
      wl1, al1, wl2, al2, stats, wt1, wt2, a1, a2);
  k_conv<false><<<1024, 256, 0, stream>>>(a1, wt1, stats, a2, nullptr, nullptr);
  k_conv<true><<<1024, 256, 0, stream>>>(a2, wt2, stats, nullptr, x, out);
}

// Round 6
// 371.702 us; speedup vs baseline: 1.4404x; 1.4404x over previous
//
#include <hip/hip_runtime.h>
#include <stdint.h>

#define EPSF 1e-5f

typedef _Float16 h8_t __attribute__((ext_vector_type(8)));
typedef float f4_t __attribute__((ext_vector_type(4)));

#define BB 64
#define CC 256
#define HH 32
#define WW 32
#define HP 34
#define WP 34
#define PADIMG (HP*WP*CC)      // halfwords per image
#define PADTOT (BB*PADIMG)

// ---- stats layout (float offsets); every slot written every launch
#define S_GSUM   0     // 64: per-group sum |w1|
#define S_GMAX   64    // 64: per-group max |w1|
#define S_W1S    128   // 64
#define S_W1Q    192   // 64
#define S_W2S    256   // 64
#define S_W2Q    320   // 64
#define S_PA2    384   // 3 (written by fused block 0, read by conv1)
#define S_INDCH  400   // 256
#define S_BN2SC  656   // 256
#define S_BN2SH  912   // 256

// ---- ws byte offsets
#define OFF_STATS 0
#define OFF_A1    8192
#define OFF_A2    (OFF_A1 + PADTOT*2)
#define OFF_W1T   (OFF_A2 + PADTOT*2)
#define OFF_W2T   (OFF_W1T + 9*CC*CC*2)

__device__ __forceinline__ void async_load16(void* lds, const void* g) {
  __builtin_amdgcn_global_load_lds(
      reinterpret_cast<uint32_t __attribute__((address_space(1)))*>((uintptr_t)g),
      reinterpret_cast<uint32_t __attribute__((address_space(3)))*>((uint32_t)(uintptr_t)lds),
      16, 0, 0);
}

#define WAITV(N) asm volatile("s_waitcnt vmcnt(" #N ")" ::: "memory")

__device__ __forceinline__ float wave_sum(float v) {
  for (int o = 32; o; o >>= 1) v += __shfl_down(v, o);
  return v;
}
__device__ __forceinline__ float wave_max(float v) {
  for (int o = 32; o; o >>= 1) v = fmaxf(v, __shfl_down(v, o));
  return v;
}

__device__ __forceinline__ void softmax3(const float* l, float* out) {
  float m = fmaxf(fmaxf(l[0], l[1]), l[2]);
  float e0 = expf(l[0] - m), e1 = expf(l[1] - m), e2 = expf(l[2] - m);
  float inv = 1.f / (e0 + e1 + e2);
  out[0] = e0 * inv; out[1] = e1 * inv; out[2] = e2 * inv;
}

// quant-mix helper (activations): clip[0,1] then 2/4/8-bit STE mix
__device__ __forceinline__ float qmix_act(float v, float p0, float p1, float p2) {
  float cl = fminf(fmaxf(v, 0.f), 1.f);
  return p0 * (rintf(cl * 3.f) / 3.f) + p1 * (rintf(cl * 15.f) / 15.f)
       + p2 * (rintf(cl * 255.f) / 255.f);
}

// ---------------- per-group stats: one pass over w1 and w2 ----------------
__global__ void k_stats(const float* __restrict__ w1, const float* __restrict__ w2,
                        float* stats) {
  __shared__ float red[4][4];
  int bid = blockIdx.x, t = threadIdx.x;
  int lane = t & 63, w = t >> 6;
  if (bid < 64) {
    const float* p = w1 + bid * 9216;
    float sa = 0.f, s = 0.f, q = 0.f, mx = 0.f;
    for (int i = t; i < 9216; i += 256) {
      float v = p[i];
      float a = fabsf(v);
      sa += a; s += v; q += v * v; mx = fmaxf(mx, a);
    }
    sa = wave_sum(sa); s = wave_sum(s); q = wave_sum(q); mx = wave_max(mx);
    if (lane == 0) { red[w][0] = sa; red[w][1] = s; red[w][2] = q; red[w][3] = mx; }
    __syncthreads();
    if (t == 0) {
      float a = 0, b = 0, c = 0, d = 0;
      for (int k = 0; k < 4; ++k) {
        a += red[k][0]; b += red[k][1]; c += red[k][2]; d = fmaxf(d, red[k][3]);
      }
      stats[S_GSUM + bid] = a;
      stats[S_W1S + bid] = b;
      stats[S_W1Q + bid] = c;
      stats[S_GMAX + bid] = d;
    }
  } else {
    int g = bid - 64;
    const float* p = w2 + (size_t)t * 2304 + g * 36;
    float s = 0.f, q = 0.f;
#pragma unroll
    for (int i = 0; i < 36; ++i) { float v = p[i]; s += v; q += v * v; }
    s = wave_sum(s); q = wave_sum(q);
    if (lane == 0) { red[w][0] = s; red[w][1] = q; }
    __syncthreads();
    if (t == 0) {
      float a = 0, b = 0;
      for (int k = 0; k < 4; ++k) { a += red[k][0]; b += red[k][1]; }
      stats[S_W2S + g] = a;
      stats[S_W2Q + g] = b;
    }
  }
}

// ---------------- fused prep + wprep + aprep (+ borders) ----------------
// block 0          : conv1 epilogue consts (indicator, bn2, pa2)
// blocks 1..64     : weight quant+mix, 8 filters/block (32 blocks per tensor)
//                    -> fp16 [e][ci_oct][co][8], stores coalesce to 128B bursts
// blocks 65..2112  : bn1+relu+qmix act -> fp16 padded NHWC
// blocks 2113..2240: border zeroing
#define WPS 264
#define APR_STRIDE 264
__global__ void k_fused(const float* __restrict__ w1, const float* __restrict__ w2,
                        const float* __restrict__ xin, const float* __restrict__ thr_p,
                        const float* __restrict__ bn1g, const float* __restrict__ bn1b,
                        const float* __restrict__ bn1m, const float* __restrict__ bn1v,
                        const float* __restrict__ bn2g, const float* __restrict__ bn2b,
                        const float* __restrict__ bn2m, const float* __restrict__ bn2v,
                        const float* __restrict__ wl1, const float* __restrict__ al1,
                        const float* __restrict__ wl2, const float* __restrict__ al2,
                        float* __restrict__ stats,
                        _Float16* __restrict__ wt1, _Float16* __restrict__ wt2,
                        _Float16* __restrict__ a1, _Float16* __restrict__ a2) {
  int bid = blockIdx.x, t = threadIdx.x;

  if (bid == 0) {
    __shared__ float sind[64];
    if (t < 64) {
      float thr = thr_p[0];
      float mx = wave_max(stats[S_GMAX + t]);
      mx = __shfl(mx, 0);
      float norm = stats[S_GSUM + t] / mx / 9216.0f;
      float soft = 1.f / (1.f + expf(-(norm - thr)));
      float hard = (norm > thr) ? 1.f : 0.f;
      sind[t] = (hard - soft) + soft;
    }
    __syncthreads();
    stats[S_INDCH + t] = sind[t >> 2];
    float sc2 = bn2g[t] * (1.f / sqrtf(bn2v[t] + EPSF));
    stats[S_BN2SC + t] = sc2;
    stats[S_BN2SH + t] = bn2b[t] - bn2m[t] * sc2;
    if (t == 0) softmax3(al2, stats + S_PA2);
    return;
  }

  if (bid <= 64) {
    // ---- weight prep: 8 filters per block, 32 blocks per tensor
    __shared__ __attribute__((aligned(16))) _Float16 lds[8 * 9 * WPS];
    __shared__ float sM, sSD, sP[3];
    int which = (bid - 1) >> 5;            // 0: blocks 1..32 (w1), 1: 33..64 (w2)
    int o0 = ((bid - 1) & 31) * 8;         // first of 8 filters (0..248)
    if (t < 64) {
      float thr = thr_p[0];
      float mx = wave_max(stats[S_GMAX + t]);
      mx = __shfl(mx, 0);
      float norm = stats[S_GSUM + t] / mx / 9216.0f;
      float soft = 1.f / (1.f + expf(-(norm - thr)));
      float hard = (norm > thr) ? 1.f : 0.f;
      float iv = (hard - soft) + soft;
      float gate = (iv > 0.f) ? 1.f : 0.f;
      float ng = wave_sum(gate);
      float s = wave_sum(gate * stats[(which ? S_W2S : S_W1S) + t]);
      float q = wave_sum(gate * stats[(which ? S_W2Q : S_W1Q) + t]);
      if (t == 0) {
        float cnt = ng * 9216.0f;
        float m = s / cnt;
        float v = (q - cnt * m * m) / (cnt - 1.0f);
        sM = m; sSD = sqrtf(fmaxf(v, 0.f));
        softmax3(which ? wl2 : wl1, sP);
      }
    }
    __syncthreads();
    const float* w = (which ? w2 : w1) + (size_t)o0 * 2304;
    float mean = sM, sd = sSD + EPSF;
    float p0 = sP[0], p1 = sP[1], p2 = sP[2];
#pragma unroll
    for (int it = 0; it < 72; ++it) {
      int f = it * 256 + t;          // 0..18431 over 8 filters x 2304
      float v = w[f];
      float wn = fminf(fmaxf((v - mean) / sd, -1.f), 1.f);
      float u0 = rintf((wn + 1.f) * 0.5f * 3.f) / 3.f;
      float u1 = rintf((wn + 1.f) * 0.5f * 15.f) / 15.f;
      float u2 = rintf((wn + 1.f) * 0.5f * 255.f) / 255.f;
      float mix = p0 * (2.f * u0 - 1.f) + p1 * (2.f * u1 - 1.f) + p2 * (2.f * u2 - 1.f);
      int ff = f / 2304;
      int rem = f - 2304 * ff;       // ci*9 + e
      int ci = rem / 9;
      int e = rem - 9 * ci;
      lds[(ff * 9 + e) * WPS + ci] = (_Float16)mix;
    }
    __syncthreads();
    // store layout: [e][cq(32)][co(256)][8]; 8 filters -> 128B bursts
    _Float16* dstW = (which ? wt2 : wt1);
#pragma unroll
    for (int it = 0; it < 9; ++it) {
      int qid = it * 256 + t;        // 0..2303
      int ff = qid & 7, pair = qid >> 3;
      int e = pair >> 5, cq = pair & 31;
      *(h8_t*)(dstW + ((size_t)(e * 32 + cq) * 256 + o0 + ff) * 8) =
          *(const h8_t*)(lds + (ff * 9 + e) * WPS + cq * 8);
    }
    return;
  }

  int ab = bid - 65;
  if (ab >= BB * HH) {
    // ---- border zeroing
    int b = ab - BB * HH;            // 0..127
    _Float16* img = (b >= BB ? a2 : a1) + (size_t)(b & 63) * PADIMG;
    uint64_t* u = (uint64_t*)img;
#pragma unroll
    for (int it = 0; it < 17; ++it) {
      int idx = it * 256 + t;          // 0..4351: rows 0 & 33 (full)
      int r33 = (idx >= 2176);
      u[(size_t)(r33 ? 33 * WP * 64 : 0) + (idx - (r33 ? 2176 : 0))] = 0ull;
    }
#pragma unroll
    for (int it = 0; it < 16; ++it) {
      int idx = it * 256 + t;          // 0..4095: cols 0/33 rows 1..32
      int p = idx >> 6;
      int y = 1 + (p >> 1), x = (p & 1) ? 33 : 0;
      u[(size_t)(y * WP + x) * 64 + (idx & 63)] = 0ull;
    }
    return;
  }

  // ---- act prep
  __shared__ __attribute__((aligned(16))) _Float16 lds[32 * APR_STRIDE];
  __shared__ float sBsc[256], sBsh[256], sPa[3];
  {
    float sc1 = bn1g[t] * (1.f / sqrtf(bn1v[t] + EPSF));
    sBsc[t] = sc1;
    sBsh[t] = bn1b[t] - bn1m[t] * sc1;
    if (t == 0) softmax3(al1, sPa);
  }
  __syncthreads();
  int n = ab >> 5, y = ab & 31;
  int x4 = (t & 7) * 4, c0 = t >> 3;
  float pa0 = sPa[0], pa1 = sPa[1], pa2 = sPa[2];
#pragma unroll
  for (int it = 0; it < 8; ++it) {
    int c = it * 32 + c0;
    const float* src = xin + ((size_t)(n * CC + c) * HH + y) * WW + x4;
    float4 v = *(const float4*)src;
    float sc = sBsc[c], sh = sBsh[c];
#pragma unroll
    for (int k = 0; k < 4; ++k) {
      float q = qmix_act((&v.x)[k] * sc + sh, pa0, pa1, pa2);
      lds[(x4 + k) * APR_STRIDE + c] = (_Float16)q;
    }
  }
  __syncthreads();
  _Float16* orow = a1 + ((size_t)(n * HP + (y + 1)) * WP + 1) * CC;
#pragma unroll
  for (int it = 0; it < 4; ++it) {
    int qid = it * 256 + t;
    int xx = qid >> 5, c8 = (qid & 31) * 8;
    *(h8_t*)(orow + xx * CC + c8) = *(const h8_t*)(lds + xx * APR_STRIDE + c8);
  }
}

// ---------------- implicit-GEMM conv, 128x128 tile, fp16 MFMA ----------------
// Weights-direct schedule (R3) with natural register reduction:
//  - LDS holds ONLY the act tile (staged once per kc, 28 KB) -> 2 barriers/kc
//  - weight B-fragments straight from global (L2-resident [e][cq][co][8]) into
//    double-buffered registers; counted vmcnt, never drains mid-loop
//  - NO __launch_bounds__ minimum (R5: min=4 forced a 64-VGPR target and
//    ~2KB/thread scratch spill -> 0.5 GB HBM traffic per dispatch)
//  - faB prefetch path removed: it held 16 extra VGPRs live across the
//    kc-boundary barrier (R3's 132-VGPR peak); simpler boundary keeps the
//    same vmcnt ledger with lower peak pressure
template <bool SW>
__global__ __launch_bounds__(256) void k_conv(
    const _Float16* __restrict__ act,   // padded NHWC acts
    const _Float16* __restrict__ wts,   // [9][32][256][8] fp16
    const float* __restrict__ stats,
    _Float16* __restrict__ a2out,
    const float* __restrict__ resid,
    float* __restrict__ out) {
  __shared__ __attribute__((aligned(16))) _Float16 AT[224 * 64];   // act tile (rows 204..223 pad)
  const int tid = threadIdx.x;
  const int lane = tid & 63, wid = tid >> 6;
  const int xcd = blockIdx.x & 7;
  const int j = blockIdx.x >> 3;          // 0..127
  const int blk_co = j >> 6;
  const int blk_m = xcd * 64 + (j & 63);

  // ---- act tile geometry: 128 m-values = 4 rows of one image
  const int n0 = blk_m >> 3;
  const int y0 = (blk_m & 7) * 4;
  const _Float16* actbase = act + (size_t)(n0 * HP + y0) * WP * CC;

  const int wr = wid >> 1, wc = wid & 1;
  const int mrow = (SW ? wc : wr) * 64;   // act-operand row block
  const int wrow = (SW ? wr : wc) * 64;   // weight-operand co block (within 128)
  const int ksl = lane >> 4;              // k-octet (8-ch) within 32-ch step

  int trbase[4];
#pragma unroll
  for (int i = 0; i < 4; ++i) {
    int r = mrow + i * 16 + (lane & 15);
    trbase[i] = (r >> 5) * 34 + (r & 31);           // tile row for tap (0,0)
  }
  // per-lane halfword offset into weight layout [e][cq][co][8]
  const unsigned vbase = (unsigned)(ksl * 256 + blk_co * 128 + wrow + (lane & 15)) * 8u;

  f4_t acc[4][4];
  const f4_t z4 = {0.f, 0.f, 0.f, 0.f};
#pragma unroll
  for (int i = 0; i < 4; ++i)
#pragma unroll
    for (int j2 = 0; j2 < 4; ++j2) acc[i][j2] = z4;

  auto stageA = [&](int kcn) {
    const int kb = kcn * 64;
#pragma unroll
    for (int it = 0; it < 7; ++it) {
      int l = it * 256 + tid;                 // 1792 loads (uniform per wave)
      int tr = l >> 3, gg = l & 7;
      int yl = tr / 34, px = tr - yl * 34;
      async_load16(AT + l * 8,
                   actbase + ((size_t)yl * WP + px) * CC + kb + ((gg ^ (tr & 7)) * 8));
    }
  };

  h8_t fwA[4], fwB[4];
  auto loadW = [&](h8_t* dst, int e, int kcn, int kk) {
    const _Float16* p = wts + (size_t)((e * 32 + kcn * 8 + kk * 4) * 2048) + vbase;
#pragma unroll
    for (int i = 0; i < 4; ++i)
      dst[i] = *(const h8_t*)(p + i * 128);
  };

  auto step = [&](const h8_t* fw, int e, int kk) {
    const int de = (e / 3) * 34 + (e % 3);
    h8_t fa[4];
#pragma unroll
    for (int i = 0; i < 4; ++i) {
      int tr = trbase[i] + de;
      fa[i] = *(const h8_t*)(AT + ((tr * 64 + ((ksl ^ (tr & 7)) * 8)) ^ (kk * 32)));
    }
    __builtin_amdgcn_s_setprio(1);
#pragma unroll
    for (int i = 0; i < 4; ++i)
#pragma unroll
      for (int j2 = 0; j2 < 4; ++j2)
        acc[i][j2] = __builtin_amdgcn_mfma_f32_16x16x32_f16(
            SW ? fw[i] : fa[i], SW ? fa[j2] : fw[j2], acc[i][j2], 0, 0, 0);
    __builtin_amdgcn_s_setprio(0);
  };

  // prologue: queue = [stageA(7), fwA(4), fwB(4)]
  stageA(0);
  loadW(fwA, 0, 0, 0);
  loadW(fwB, 0, 0, 1);

#pragma unroll 1
  for (int kc = 0; kc < 4; ++kc) {
    // drain own stageA (+previous fwA); leaves newest 4 (fwB) in flight
    WAITV(4);
    __builtin_amdgcn_s_barrier();
    __builtin_amdgcn_sched_barrier(0);
#pragma unroll
    for (int t2 = 0; t2 < 9; ++t2) {
      if (t2 < 8) {
        step(fwA, t2, 0);
        loadW(fwA, t2 + 1, kc, 0);
        step(fwB, t2, 1);
        loadW(fwB, t2 + 1, kc, 1);
      } else if (kc < 3) {
        step(fwA, 8, 0);
        loadW(fwA, 0, kc + 1, 0);
        step(fwB, 8, 1);
        loadW(fwB, 0, kc + 1, 1);
        // all ds_reads of AT(kc) done before next stage overwrites it
        asm volatile("s_waitcnt lgkmcnt(0)" ::: "memory");
        __builtin_amdgcn_sched_barrier(0);
        __builtin_amdgcn_s_barrier();
        __builtin_amdgcn_sched_barrier(0);
        stageA(kc + 1);
      } else {
        step(fwA, 8, 0);
        step(fwB, 8, 1);
      }
    }
  }

  const int quad = lane >> 4;
  const int cq = lane & 15;
  if (!SW) {
    const float pa0 = stats[S_PA2], pa1 = stats[S_PA2 + 1], pa2 = stats[S_PA2 + 2];
#pragma unroll
    for (int j2 = 0; j2 < 4; ++j2) {
      const int co = blk_co * 128 + wc * 64 + j2 * 16 + cq;
      const float sc = stats[S_BN2SC + co];
      const float sh = stats[S_BN2SH + co];
      const float ic = stats[S_INDCH + co];
#pragma unroll
      for (int i = 0; i < 4; ++i) {
        const int mbase = blk_m * 128 + wr * 64 + i * 16 + quad * 4;
#pragma unroll
        for (int rg = 0; rg < 4; ++rg) {
          const int m = mbase + rg;
          const int n = m >> 10, y = (m >> 5) & 31, x = m & 31;
          float h = fmaxf(acc[i][j2][rg] * sc + sh, 0.f) * ic;
          float q = qmix_act(h, pa0, pa1, pa2);
          a2out[((size_t)(n * HP + y + 1) * WP + (x + 1)) * CC + co] = (_Float16)q;
        }
      }
    }
  } else {
#pragma unroll
    for (int j2 = 0; j2 < 4; ++j2) {
      const int m = blk_m * 128 + wc * 64 + j2 * 16 + cq;
      const int n = m >> 10, y = (m >> 5) & 31, x = m & 31;
#pragma unroll
      for (int i = 0; i < 4; ++i) {
        const int cobase = blk_co * 128 + wr * 64 + i * 16 + quad * 4;
#pragma unroll
        for (int rg = 0; rg < 4; ++rg) {
          const int co = cobase + rg;
          const int idx = ((n * CC + co) << 10) + (y << 5) + x;
          out[idx] = acc[i][j2][rg] + resid[idx];
        }
      }
    }
  }
}

extern "C" void kernel_launch(void* const* d_in, const int* in_sizes, int n_in,
                              void* d_out, int out_size, void* d_ws, size_t ws_size,
                              hipStream_t stream) {
  const float* x    = (const float*)d_in[0];
  const float* w1   = (const float*)d_in[1];
  const float* w2   = (const float*)d_in[2];
  const float* bn1g = (const float*)d_in[3];
  const float* bn1b = (const float*)d_in[4];
  const float* bn1m = (const float*)d_in[5];
  const float* bn1v = (const float*)d_in[6];
  const float* bn2g = (const float*)d_in[7];
  const float* bn2b = (const float*)d_in[8];
  const float* bn2m = (const float*)d_in[9];
  const float* bn2v = (const float*)d_in[10];
  const float* thr  = (const float*)d_in[11];
  const float* wl1  = (const float*)d_in[12];
  const float* al1  = (const float*)d_in[13];
  const float* wl2  = (const float*)d_in[14];
  const float* al2  = (const float*)d_in[15];

  char* ws = (char*)d_ws;
  float* stats = (float*)(ws + OFF_STATS);
  _Float16* a1 = (_Float16*)(ws + OFF_A1);
  _Float16* a2 = (_Float16*)(ws + OFF_A2);
  _Float16* wt1 = (_Float16*)(ws + OFF_W1T);
  _Float16* wt2 = (_Float16*)(ws + OFF_W2T);
  float* out = (float*)d_out;

  k_stats<<<128, 256, 0, stream>>>(w1, w2, stats);
  k_fused<<<1 + 64 + BB * HH + 128, 256, 0, stream>>>(
      w1, w2, x, thr, bn1g, bn1b, bn1m, bn1v, bn2g, bn2b, bn2m, bn2v,
      wl1, al1, wl2, al2, stats, wt1, wt2, a1, a2);
  k_conv<false><<<1024, 256, 0, stream>>>(a1, wt1, stats, a2, nullptr, nullptr);
  k_conv<true><<<1024, 256, 0, stream>>>(a2, wt2, stats, nullptr, x, out);
}

// Round 7
// 349.201 us; speedup vs baseline: 1.5333x; 1.0644x over previous
//
#include <hip/hip_runtime.h>
#include <stdint.h>

#define EPSF 1e-5f

typedef _Float16 h8_t __attribute__((ext_vector_type(8)));
typedef float f4_t __attribute__((ext_vector_type(4)));

#define BB 64
#define CC 256
#define HH 32
#define WW 32
#define HP 34
#define WP 34
#define PADIMG (HP*WP*CC)      // halfwords per image
#define PADTOT (BB*PADIMG)

// ---- stats layout (float offsets); every slot written every launch
#define S_GSUM   0     // 64: per-group sum |w1|
#define S_GMAX   64    // 64: per-group max |w1|
#define S_W1S    128   // 64
#define S_W1Q    192   // 64
#define S_W2S    256   // 64
#define S_W2Q    320   // 64
#define S_PA2    384   // 3 (written by fused block 0, read by conv1)
#define S_INDCH  400   // 256
#define S_BN2SC  656   // 256
#define S_BN2SH  912   // 256

// ---- ws byte offsets
#define OFF_STATS 0
#define OFF_A1    8192
#define OFF_A2    (OFF_A1 + PADTOT*2)
#define OFF_W1T   (OFF_A2 + PADTOT*2)
#define OFF_W2T   (OFF_W1T + 9*CC*CC*2)

__device__ __forceinline__ void async_load16(void* lds, const void* g) {
  __builtin_amdgcn_global_load_lds(
      reinterpret_cast<uint32_t __attribute__((address_space(1)))*>((uintptr_t)g),
      reinterpret_cast<uint32_t __attribute__((address_space(3)))*>((uint32_t)(uintptr_t)lds),
      16, 0, 0);
}

#define WAITV(N) asm volatile("s_waitcnt vmcnt(" #N ")" ::: "memory")

__device__ __forceinline__ float wave_sum(float v) {
  for (int o = 32; o; o >>= 1) v += __shfl_down(v, o);
  return v;
}
__device__ __forceinline__ float wave_max(float v) {
  for (int o = 32; o; o >>= 1) v = fmaxf(v, __shfl_down(v, o));
  return v;
}

__device__ __forceinline__ void softmax3(const float* l, float* out) {
  float m = fmaxf(fmaxf(l[0], l[1]), l[2]);
  float e0 = expf(l[0] - m), e1 = expf(l[1] - m), e2 = expf(l[2] - m);
  float inv = 1.f / (e0 + e1 + e2);
  out[0] = e0 * inv; out[1] = e1 * inv; out[2] = e2 * inv;
}

// quant-mix helper (activations): clip[0,1] then 2/4/8-bit STE mix
__device__ __forceinline__ float qmix_act(float v, float p0, float p1, float p2) {
  float cl = fminf(fmaxf(v, 0.f), 1.f);
  return p0 * (rintf(cl * 3.f) / 3.f) + p1 * (rintf(cl * 15.f) / 15.f)
       + p2 * (rintf(cl * 255.f) / 255.f);
}

// ---------------- per-group stats: one pass over w1 and w2 ----------------
__global__ void k_stats(const float* __restrict__ w1, const float* __restrict__ w2,
                        float* stats) {
  __shared__ float red[4][4];
  int bid = blockIdx.x, t = threadIdx.x;
  int lane = t & 63, w = t >> 6;
  if (bid < 64) {
    const float* p = w1 + bid * 9216;
    float sa = 0.f, s = 0.f, q = 0.f, mx = 0.f;
    for (int i = t; i < 9216; i += 256) {
      float v = p[i];
      float a = fabsf(v);
      sa += a; s += v; q += v * v; mx = fmaxf(mx, a);
    }
    sa = wave_sum(sa); s = wave_sum(s); q = wave_sum(q); mx = wave_max(mx);
    if (lane == 0) { red[w][0] = sa; red[w][1] = s; red[w][2] = q; red[w][3] = mx; }
    __syncthreads();
    if (t == 0) {
      float a = 0, b = 0, c = 0, d = 0;
      for (int k = 0; k < 4; ++k) {
        a += red[k][0]; b += red[k][1]; c += red[k][2]; d = fmaxf(d, red[k][3]);
      }
      stats[S_GSUM + bid] = a;
      stats[S_W1S + bid] = b;
      stats[S_W1Q + bid] = c;
      stats[S_GMAX + bid] = d;
    }
  } else {
    int g = bid - 64;
    const float* p = w2 + (size_t)t * 2304 + g * 36;
    float s = 0.f, q = 0.f;
#pragma unroll
    for (int i = 0; i < 36; ++i) { float v = p[i]; s += v; q += v * v; }
    s = wave_sum(s); q = wave_sum(q);
    if (lane == 0) { red[w][0] = s; red[w][1] = q; }
    __syncthreads();
    if (t == 0) {
      float a = 0, b = 0;
      for (int k = 0; k < 4; ++k) { a += red[k][0]; b += red[k][1]; }
      stats[S_W2S + g] = a;
      stats[S_W2Q + g] = b;
    }
  }
}

// ---------------- fused prep + wprep + aprep (+ borders) ----------------
// block 0          : conv1 epilogue consts (indicator, bn2, pa2)
// blocks 1..64     : weight quant+mix, 8 filters/block (32 blocks per tensor)
//                    -> fp16 LINEAR-STREAM layout [chunk(72)][ksl(4)][co(256)][8]
//                    where chunk = (kc*9+e)*2+kk  (conv reads chunks 0..71 in
//                    order with a single bumped pointer)
// blocks 65..2112  : bn1+relu+qmix act -> fp16 padded NHWC
// blocks 2113..2240: border zeroing
#define WPS 264
#define APR_STRIDE 264
__global__ void k_fused(const float* __restrict__ w1, const float* __restrict__ w2,
                        const float* __restrict__ xin, const float* __restrict__ thr_p,
                        const float* __restrict__ bn1g, const float* __restrict__ bn1b,
                        const float* __restrict__ bn1m, const float* __restrict__ bn1v,
                        const float* __restrict__ bn2g, const float* __restrict__ bn2b,
                        const float* __restrict__ bn2m, const float* __restrict__ bn2v,
                        const float* __restrict__ wl1, const float* __restrict__ al1,
                        const float* __restrict__ wl2, const float* __restrict__ al2,
                        float* __restrict__ stats,
                        _Float16* __restrict__ wt1, _Float16* __restrict__ wt2,
                        _Float16* __restrict__ a1, _Float16* __restrict__ a2) {
  int bid = blockIdx.x, t = threadIdx.x;

  if (bid == 0) {
    __shared__ float sind[64];
    if (t < 64) {
      float thr = thr_p[0];
      float mx = wave_max(stats[S_GMAX + t]);
      mx = __shfl(mx, 0);
      float norm = stats[S_GSUM + t] / mx / 9216.0f;
      float soft = 1.f / (1.f + expf(-(norm - thr)));
      float hard = (norm > thr) ? 1.f : 0.f;
      sind[t] = (hard - soft) + soft;
    }
    __syncthreads();
    stats[S_INDCH + t] = sind[t >> 2];
    float sc2 = bn2g[t] * (1.f / sqrtf(bn2v[t] + EPSF));
    stats[S_BN2SC + t] = sc2;
    stats[S_BN2SH + t] = bn2b[t] - bn2m[t] * sc2;
    if (t == 0) softmax3(al2, stats + S_PA2);
    return;
  }

  if (bid <= 64) {
    // ---- weight prep: 8 filters per block, 32 blocks per tensor
    __shared__ __attribute__((aligned(16))) _Float16 lds[8 * 9 * WPS];
    __shared__ float sM, sSD, sP[3];
    int which = (bid - 1) >> 5;            // 0: blocks 1..32 (w1), 1: 33..64 (w2)
    int o0 = ((bid - 1) & 31) * 8;         // first of 8 filters (0..248)
    if (t < 64) {
      float thr = thr_p[0];
      float mx = wave_max(stats[S_GMAX + t]);
      mx = __shfl(mx, 0);
      float norm = stats[S_GSUM + t] / mx / 9216.0f;
      float soft = 1.f / (1.f + expf(-(norm - thr)));
      float hard = (norm > thr) ? 1.f : 0.f;
      float iv = (hard - soft) + soft;
      float gate = (iv > 0.f) ? 1.f : 0.f;
      float ng = wave_sum(gate);
      float s = wave_sum(gate * stats[(which ? S_W2S : S_W1S) + t]);
      float q = wave_sum(gate * stats[(which ? S_W2Q : S_W1Q) + t]);
      if (t == 0) {
        float cnt = ng * 9216.0f;
        float m = s / cnt;
        float v = (q - cnt * m * m) / (cnt - 1.0f);
        sM = m; sSD = sqrtf(fmaxf(v, 0.f));
        softmax3(which ? wl2 : wl1, sP);
      }
    }
    __syncthreads();
    const float* w = (which ? w2 : w1) + (size_t)o0 * 2304;
    float mean = sM, sd = sSD + EPSF;
    float p0 = sP[0], p1 = sP[1], p2 = sP[2];
#pragma unroll
    for (int it = 0; it < 72; ++it) {
      int f = it * 256 + t;          // 0..18431 over 8 filters x 2304
      float v = w[f];
      float wn = fminf(fmaxf((v - mean) / sd, -1.f), 1.f);
      float u0 = rintf((wn + 1.f) * 0.5f * 3.f) / 3.f;
      float u1 = rintf((wn + 1.f) * 0.5f * 15.f) / 15.f;
      float u2 = rintf((wn + 1.f) * 0.5f * 255.f) / 255.f;
      float mix = p0 * (2.f * u0 - 1.f) + p1 * (2.f * u1 - 1.f) + p2 * (2.f * u2 - 1.f);
      int ff = f / 2304;
      int rem = f - 2304 * ff;       // ci*9 + e
      int ci = rem / 9;
      int e = rem - 9 * ci;
      lds[(ff * 9 + e) * WPS + ci] = (_Float16)mix;
    }
    __syncthreads();
    // store: chunk = (kc*9+e)*2+kk; within chunk [ksl(4)][co(256)][8]
    // cq (ci octet 0..31): kc=cq>>3, kk=(cq>>2)&1, ksl=cq&3
    _Float16* dstW = (which ? wt2 : wt1);
#pragma unroll
    for (int it = 0; it < 9; ++it) {
      int qid = it * 256 + t;        // 0..2303
      int ff = qid & 7, pair = qid >> 3;
      int e = pair >> 5, cq = pair & 31;
      int kc2 = cq >> 3, kk2 = (cq >> 2) & 1, ks2 = cq & 3;
      size_t off = (size_t)((((kc2 * 9 + e) * 2 + kk2) * 4 + ks2)) * 2048
                 + (size_t)(o0 + ff) * 8;
      *(h8_t*)(dstW + off) = *(const h8_t*)(lds + (ff * 9 + e) * WPS + cq * 8);
    }
    return;
  }

  int ab = bid - 65;
  if (ab >= BB * HH) {
    // ---- border zeroing
    int b = ab - BB * HH;            // 0..127
    _Float16* img = (b >= BB ? a2 : a1) + (size_t)(b & 63) * PADIMG;
    uint64_t* u = (uint64_t*)img;
#pragma unroll
    for (int it = 0; it < 17; ++it) {
      int idx = it * 256 + t;          // 0..4351: rows 0 & 33 (full)
      int r33 = (idx >= 2176);
      u[(size_t)(r33 ? 33 * WP * 64 : 0) + (idx - (r33 ? 2176 : 0))] = 0ull;
    }
#pragma unroll
    for (int it = 0; it < 16; ++it) {
      int idx = it * 256 + t;          // 0..4095: cols 0/33 rows 1..32
      int p = idx >> 6;
      int y = 1 + (p >> 1), x = (p & 1) ? 33 : 0;
      u[(size_t)(y * WP + x) * 64 + (idx & 63)] = 0ull;
    }
    return;
  }

  // ---- act prep
  __shared__ __attribute__((aligned(16))) _Float16 lds[32 * APR_STRIDE];
  __shared__ float sBsc[256], sBsh[256], sPa[3];
  {
    float sc1 = bn1g[t] * (1.f / sqrtf(bn1v[t] + EPSF));
    sBsc[t] = sc1;
    sBsh[t] = bn1b[t] - bn1m[t] * sc1;
    if (t == 0) softmax3(al1, sPa);
  }
  __syncthreads();
  int n = ab >> 5, y = ab & 31;
  int x4 = (t & 7) * 4, c0 = t >> 3;
  float pa0 = sPa[0], pa1 = sPa[1], pa2 = sPa[2];
#pragma unroll
  for (int it = 0; it < 8; ++it) {
    int c = it * 32 + c0;
    const float* src = xin + ((size_t)(n * CC + c) * HH + y) * WW + x4;
    float4 v = *(const float4*)src;
    float sc = sBsc[c], sh = sBsh[c];
#pragma unroll
    for (int k = 0; k < 4; ++k) {
      float q = qmix_act((&v.x)[k] * sc + sh, pa0, pa1, pa2);
      lds[(x4 + k) * APR_STRIDE + c] = (_Float16)q;
    }
  }
  __syncthreads();
  _Float16* orow = a1 + ((size_t)(n * HP + (y + 1)) * WP + 1) * CC;
#pragma unroll
  for (int it = 0; it < 4; ++it) {
    int qid = it * 256 + t;
    int xx = qid >> 5, c8 = (qid & 31) * 8;
    *(h8_t*)(orow + xx * CC + c8) = *(const h8_t*)(lds + xx * APR_STRIDE + c8);
  }
}

// ---------------- implicit-GEMM conv, 128x128 tile, fp16 MFMA ----------------
// Register-lean weights-direct schedule:
//  - LDS: act tile only (28 KB, staged once per kc) -> 10 barriers total
//  - weights: ONE linearly-bumped pointer over [chunk 0..71][ksl][co][8];
//    runtime (unroll-1) e-loop so the compiler keeps 2 address VGPRs, not 16
//    (R6 lesson: unrolled per-iter global addresses all stay live -> 172 VGPR)
//  - race-free kc boundary: reads-drain barrier -> stageA -> fw prefetch ->
//    WAITV(8) (stage oldest in FIFO -> fully drained; both fw bufs in flight)
//    -> barrier  (fixes R6's latent stage/ds_read race)
template <bool SW>
__global__ __launch_bounds__(256) void k_conv(
    const _Float16* __restrict__ act,   // padded NHWC acts
    const _Float16* __restrict__ wts,   // [72][4][256][8] fp16 stream
    const float* __restrict__ stats,
    _Float16* __restrict__ a2out,
    const float* __restrict__ resid,
    float* __restrict__ out) {
  __shared__ __attribute__((aligned(16))) _Float16 AT[224 * 64];   // rows 204..223 pad
  const int tid = threadIdx.x;
  const int lane = tid & 63, wid = tid >> 6;
  const int xcd = blockIdx.x & 7;
  const int j = blockIdx.x >> 3;          // 0..127
  const int blk_co = j >> 6;
  const int blk_m = xcd * 64 + (j & 63);

  // ---- act tile geometry: 128 m-values = 4 rows of one image
  const int n0 = blk_m >> 3;
  const int y0 = (blk_m & 7) * 4;
  const _Float16* actbase = act + (size_t)(n0 * HP + y0) * WP * CC;

  const int wr = wid >> 1, wc = wid & 1;
  const int mrow = (SW ? wc : wr) * 64;   // act-operand row block
  const int wrow = (SW ? wr : wc) * 64;   // weight-operand co block (within 128)
  const int ksl = lane >> 4;              // k-octet (8-ch) within 32-ch step

  // single-register act row base: trbase[i] = base34 + {0,16,34,50}[i]
  const int base34 = (mrow >> 5) * 34 + (lane & 15);

  // weight stream pointer (per-lane), bumped 8192 halfwords (1 chunk) per load
  const _Float16* wptr =
      wts + (size_t)(ksl * 2048 + (blk_co * 128 + wrow + (lane & 15)) * 8);

  f4_t acc[4][4];
  const f4_t z4 = {0.f, 0.f, 0.f, 0.f};
#pragma unroll
  for (int i = 0; i < 4; ++i)
#pragma unroll
    for (int j2 = 0; j2 < 4; ++j2) acc[i][j2] = z4;

  auto stageA = [&](int kcn) {
    const int kb = kcn * 64;
#pragma unroll
    for (int it = 0; it < 7; ++it) {
      int l = it * 256 + tid;                 // 1792 loads (uniform per wave)
      int tr = l >> 3, gg = l & 7;
      int yl = tr / 34, px = tr - yl * 34;
      async_load16(AT + l * 8,
                   actbase + ((size_t)yl * WP + px) * CC + kb + ((gg ^ (tr & 7)) * 8));
    }
  };

  h8_t fwA[4], fwB[4];
  auto loadW = [&](h8_t* dst) {
#pragma unroll
    for (int i = 0; i < 4; ++i)
      dst[i] = *(const h8_t*)(wptr + i * 128);
    wptr += 8192;
  };

  // prologue: queue = [stage(7), fwA(4), fwB(4)]; WAITV(8) drains stage only
  stageA(0);
  loadW(fwA);
  loadW(fwB);
  WAITV(8);
  __builtin_amdgcn_sched_barrier(0);
  __builtin_amdgcn_s_barrier();

#pragma unroll 1
  for (int kc = 0; kc < 4; ++kc) {
#pragma unroll 1
    for (int e = 0; e < 9; ++e) {
      const int d3 = (e * 43) >> 7;          // e/3 for e in 0..8
      const int de = e + 31 * d3;            // (e/3)*34 + e%3
      const int t0 = base34 + de;
      // ---- kk=0 with fwA
      {
        h8_t fa[4];
#pragma unroll
        for (int i = 0; i < 4; ++i) {
          const int tr = t0 + (i == 0 ? 0 : i == 1 ? 16 : i == 2 ? 34 : 50);
          fa[i] = *(const h8_t*)(AT + ((tr * 64 + ((ksl ^ (tr & 7)) * 8))));
        }
        __builtin_amdgcn_s_setprio(1);
#pragma unroll
        for (int i = 0; i < 4; ++i)
#pragma unroll
          for (int j2 = 0; j2 < 4; ++j2)
            acc[i][j2] = __builtin_amdgcn_mfma_f32_16x16x32_f16(
                SW ? fwA[i] : fa[i], SW ? fa[j2] : fwA[j2], acc[i][j2], 0, 0, 0);
        __builtin_amdgcn_s_setprio(0);
      }
      if (e < 8) loadW(fwA);
      // ---- kk=1 with fwB
      {
        h8_t fa[4];
#pragma unroll
        for (int i = 0; i < 4; ++i) {
          const int tr = t0 + (i == 0 ? 0 : i == 1 ? 16 : i == 2 ? 34 : 50);
          fa[i] = *(const h8_t*)(AT + ((tr * 64 + ((ksl ^ (tr & 7)) * 8)) ^ 32));
        }
        __builtin_amdgcn_s_setprio(1);
#pragma unroll
        for (int i = 0; i < 4; ++i)
#pragma unroll
          for (int j2 = 0; j2 < 4; ++j2)
            acc[i][j2] = __builtin_amdgcn_mfma_f32_16x16x32_f16(
                SW ? fwB[i] : fa[i], SW ? fa[j2] : fwB[j2], acc[i][j2], 0, 0, 0);
        __builtin_amdgcn_s_setprio(0);
      }
      if (e < 8) loadW(fwB);
    }
    if (kc < 3) {
      // all AT(kc) ds_reads landed in regs -> safe to overwrite after barrier
      asm volatile("s_waitcnt lgkmcnt(0)" ::: "memory");
      __builtin_amdgcn_sched_barrier(0);
      __builtin_amdgcn_s_barrier();
      __builtin_amdgcn_sched_barrier(0);
      stageA(kc + 1);
      loadW(fwA);          // next kc chunks (2 loads after stage in FIFO)
      loadW(fwB);
      WAITV(8);            // drains stage(7) fully; fwA+fwB stay in flight
      __builtin_amdgcn_sched_barrier(0);
      __builtin_amdgcn_s_barrier();
    }
  }

  const int quad = lane >> 4;
  const int cq = lane & 15;
  if (!SW) {
    const float pa0 = stats[S_PA2], pa1 = stats[S_PA2 + 1], pa2 = stats[S_PA2 + 2];
#pragma unroll
    for (int j2 = 0; j2 < 4; ++j2) {
      const int co = blk_co * 128 + wc * 64 + j2 * 16 + cq;
      const float sc = stats[S_BN2SC + co];
      const float sh = stats[S_BN2SH + co];
      const float ic = stats[S_INDCH + co];
#pragma unroll
      for (int i = 0; i < 4; ++i) {
        const int mbase = blk_m * 128 + wr * 64 + i * 16 + quad * 4;
#pragma unroll
        for (int rg = 0; rg < 4; ++rg) {
          const int m = mbase + rg;
          const int n = m >> 10, y = (m >> 5) & 31, x = m & 31;
          float h = fmaxf(acc[i][j2][rg] * sc + sh, 0.f) * ic;
          float q = qmix_act(h, pa0, pa1, pa2);
          a2out[((size_t)(n * HP + y + 1) * WP + (x + 1)) * CC + co] = (_Float16)q;
        }
      }
    }
  } else {
#pragma unroll
    for (int j2 = 0; j2 < 4; ++j2) {
      const int m = blk_m * 128 + wc * 64 + j2 * 16 + cq;
      const int n = m >> 10, y = (m >> 5) & 31, x = m & 31;
#pragma unroll
      for (int i = 0; i < 4; ++i) {
        const int cobase = blk_co * 128 + wr * 64 + i * 16 + quad * 4;
#pragma unroll
        for (int rg = 0; rg < 4; ++rg) {
          const int co = cobase + rg;
          const int idx = ((n * CC + co) << 10) + (y << 5) + x;
          out[idx] = acc[i][j2][rg] + resid[idx];
        }
      }
    }
  }
}

extern "C" void kernel_launch(void* const* d_in, const int* in_sizes, int n_in,
                              void* d_out, int out_size, void* d_ws, size_t ws_size,
                              hipStream_t stream) {
  const float* x    = (const float*)d_in[0];
  const float* w1   = (const float*)d_in[1];
  const float* w2   = (const float*)d_in[2];
  const float* bn1g = (const float*)d_in[3];
  const float* bn1b = (const float*)d_in[4];
  const float* bn1m = (const float*)d_in[5];
  const float* bn1v = (const float*)d_in[6];
  const float* bn2g = (const float*)d_in[7];
  const float* bn2b = (const float*)d_in[8];
  const float* bn2m = (const float*)d_in[9];
  const float* bn2v = (const float*)d_in[10];
  const float* thr  = (const float*)d_in[11];
  const float* wl1  = (const float*)d_in[12];
  const float* al1  = (const float*)d_in[13];
  const float* wl2  = (const float*)d_in[14];
  const float* al2  = (const float*)d_in[15];

  char* ws = (char*)d_ws;
  float* stats = (float*)(ws + OFF_STATS);
  _Float16* a1 = (_Float16*)(ws + OFF_A1);
  _Float16* a2 = (_Float16*)(ws + OFF_A2);
  _Float16* wt1 = (_Float16*)(ws + OFF_W1T);
  _Float16* wt2 = (_Float16*)(ws + OFF_W2T);
  float* out = (float*)d_out;

  k_stats<<<128, 256, 0, stream>>>(w1, w2, stats);
  k_fused<<<1 + 64 + BB * HH + 128, 256, 0, stream>>>(
      w1, w2, x, thr, bn1g, bn1b, bn1m, bn1v, bn2g, bn2b, bn2m, bn2v,
      wl1, al1, wl2, al2, stats, wt1, wt2, a1, a2);
  k_conv<false><<<1024, 256, 0, stream>>>(a1, wt1, stats, a2, nullptr, nullptr);
  k_conv<true><<<1024, 256, 0, stream>>>(a2, wt2, stats, nullptr, x, out);
}